// Round 14
// baseline (126.276 us; speedup 1.0000x reference)
//
#include <hip/hip_runtime.h>
#include <math.h>

#define D_MODEL 768
#define NHEAD   12
#define HD      64
#define SEQ_T   2048
#define SEQ_K   512
#define BS      8
#define EPS_COS 1e-8f
#define LOG2E   1.44269504f

typedef short  bf16x8 __attribute__((ext_vector_type(8)));
typedef float  f32x4  __attribute__((ext_vector_type(4)));

__device__ __forceinline__ ushort f2bf(float x) {
    unsigned b = __float_as_uint(x);
    return (ushort)((b + 0x7FFF + ((b >> 16) & 1)) >> 16);
}
__device__ __forceinline__ unsigned cvt_pk_bf16(float lo, float hi) {
    unsigned r;
    asm("v_cvt_pk_bf16_f32 %0, %1, %2" : "=v"(r) : "v"(lo), "v"(hi));
    return r;
}
__device__ __forceinline__ float exp2_fast(float x) {
    float r;
    asm("v_exp_f32 %0, %1" : "=v"(r) : "v"(x));
    return r;
}

// async global->LDS 16B/lane: dest = wave-uniform base + lane*16, src per-lane
__device__ __forceinline__ void async_copy16(void* lds_base, const void* g_src) {
    __builtin_amdgcn_global_load_lds(
        (const __attribute__((address_space(1))) unsigned int*)g_src,
        (__attribute__((address_space(3))) unsigned int*)lds_base,
        16, 0, 0);
}

// ---------------------------------------------------------------------------
// 4 weight tensors f32->bf16 in one launch: grid (576, 4)
// ---------------------------------------------------------------------------
__global__ __launch_bounds__(256) void cvt4_kernel(
    const float* __restrict__ s0, const float* __restrict__ s1,
    const float* __restrict__ s2, const float* __restrict__ s3,
    ushort* __restrict__ d0, ushort* __restrict__ d1,
    ushort* __restrict__ d2, ushort* __restrict__ d3)
{
    const float* s; ushort* d;
    switch (blockIdx.y) {
        case 0: s = s0; d = d0; break;
        case 1: s = s1; d = d1; break;
        case 2: s = s2; d = d2; break;
        default: s = s3; d = d3; break;
    }
    int i = blockIdx.x * 256 + threadIdx.x;
    float4 v = reinterpret_cast<const float4*>(s)[i];
    ushort4 o;
    o.x = f2bf(v.x); o.y = f2bf(v.y); o.z = f2bf(v.z); o.w = f2bf(v.w);
    reinterpret_cast<ushort4*>(d)[i] = o;
}

// ---------------------------------------------------------------------------
// 2 activation tensors f32->bf16, grid-stride: grid (2048, 2)
// (one bf16 conversion per element, amortized once — r13 lesson: f32
//  A-staging re-paid conversion 6x per element via column-block re-stages)
// ---------------------------------------------------------------------------
__global__ __launch_bounds__(256) void cvt2_kernel(
    const float* __restrict__ s0, ushort* __restrict__ d0, int n0_4,
    const float* __restrict__ s1, ushort* __restrict__ d1, int n1_4)
{
    const float* s; ushort* d; int n4;
    if (blockIdx.y == 0) { s = s0; d = d0; n4 = n0_4; }
    else                 { s = s1; d = d1; n4 = n1_4; }
    int i = blockIdx.x * 256 + threadIdx.x;
    int stride = gridDim.x * 256;
    for (; i < n4; i += stride) {
        float4 v = reinterpret_cast<const float4*>(s)[i];
        ushort4 o;
        o.x = f2bf(v.x); o.y = f2bf(v.y); o.z = f2bf(v.z); o.w = f2bf(v.w);
        reinterpret_cast<ushort4*>(d)[i] = o;
    }
}

// ---------------------------------------------------------------------------
// cosine similarity -> bsim[b][h][k] = beta[h] * log2(e) * sim(b,k)
// ---------------------------------------------------------------------------
__global__ __launch_bounds__(256) void sim_kernel(
    const float* __restrict__ pooled, const float* __restrict__ kg_key,
    const float* __restrict__ beta, float* __restrict__ bsim)
{
    int wid  = (blockIdx.x * blockDim.x + threadIdx.x) >> 6;
    int lane = threadIdx.x & 63;
    int b  = wid >> 9;
    int kk = wid & 511;
    const float* p   = pooled + (size_t)b * D_MODEL;
    const float* key = kg_key + ((size_t)b * SEQ_K + kk) * D_MODEL;
    float dpk = 0.f, dkk = 0.f, dpp = 0.f;
    for (int i = lane; i < D_MODEL; i += 64) {
        float pv = p[i], kv = key[i];
        dpk += pv * kv; dkk += kv * kv; dpp += pv * pv;
    }
    for (int off = 32; off; off >>= 1) {
        dpk += __shfl_xor(dpk, off);
        dkk += __shfl_xor(dkk, off);
        dpp += __shfl_xor(dpp, off);
    }
    if (lane == 0) {
        float np_ = fmaxf(sqrtf(dpp), EPS_COS);
        float nk_ = fmaxf(sqrtf(dkk), EPS_COS);
        float sv = (dpk / (np_ * nk_)) * LOG2E;
#pragma unroll
        for (int h = 0; h < NHEAD; ++h)
            bsim[(size_t)(b * NHEAD + h) * SEQ_K + kk] = beta[h] * sv;
    }
}

// ---------------------------------------------------------------------------
// bf16 GEMM (Q-proj / generic): out_bf = (A @ W^T + bias) * scale, 128x128
// tile, BK=64, 4 waves. 32KB LDS, launch_bounds(256,3).
// ---------------------------------------------------------------------------
__global__ __launch_bounds__(256, 3) void gemm_q_kernel(
    const ushort* __restrict__ A, const ushort* __restrict__ W,
    const float* __restrict__ bias, ushort* __restrict__ out_bf, float scale)
{
    constexpr int Kd = D_MODEL;
    __shared__ __align__(16) ushort As[128 * 64];
    __shared__ __align__(16) ushort Bs[128 * 64];
    const int tid = threadIdx.x, wid = tid >> 6, l = tid & 63;
    const int g = l >> 4, c = l & 15;
    const int m0 = blockIdx.x * 128, n0 = blockIdx.y * 128;
    const int wm = (wid >> 1) * 64, wn = (wid & 1) * 64;

    f32x4 acc[4][4] = {};

    for (int k0 = 0; k0 < Kd; k0 += 64) {
        __syncthreads();
#pragma unroll
        for (int it = 0; it < 4; ++it) {
            int L = wid * 4096 + it * 1024 + l * 16;
            int row = L >> 7;
            int gb = ((L >> 4) & 7) ^ (row & 7);
            async_copy16((char*)As + wid * 4096 + it * 1024,
                         A + (size_t)(m0 + row) * Kd + k0 + gb * 8);
        }
#pragma unroll
        for (int it = 0; it < 4; ++it) {
            int L = wid * 4096 + it * 1024 + l * 16;
            int row = L >> 7;
            int gb = ((L >> 4) & 7) ^ (row & 7);
            async_copy16((char*)Bs + wid * 4096 + it * 1024,
                         W + (size_t)(n0 + row) * Kd + k0 + gb * 8);
        }
        __syncthreads();

        bf16x8 af[4][2], bf[4][2];
#pragma unroll
        for (int mt = 0; mt < 4; ++mt)
#pragma unroll
            for (int ks = 0; ks < 2; ++ks) {
                int row = wm + mt * 16 + c;
                af[mt][ks] = *(const bf16x8*)((const char*)As + row * 128 +
                                              (((ks * 4 + g) ^ (row & 7)) << 4));
            }
#pragma unroll
        for (int nt = 0; nt < 4; ++nt)
#pragma unroll
            for (int ks = 0; ks < 2; ++ks) {
                int row = wn + nt * 16 + c;
                bf[nt][ks] = *(const bf16x8*)((const char*)Bs + row * 128 +
                                              (((ks * 4 + g) ^ (row & 7)) << 4));
            }
        __builtin_amdgcn_s_setprio(1);
#pragma unroll
        for (int mt = 0; mt < 4; ++mt)
#pragma unroll
            for (int nt = 0; nt < 4; ++nt) {
                acc[mt][nt] = __builtin_amdgcn_mfma_f32_16x16x32_bf16(
                    af[mt][0], bf[nt][0], acc[mt][nt], 0, 0, 0);
                acc[mt][nt] = __builtin_amdgcn_mfma_f32_16x16x32_bf16(
                    af[mt][1], bf[nt][1], acc[mt][nt], 0, 0, 0);
            }
        __builtin_amdgcn_s_setprio(0);
    }

#pragma unroll
    for (int mt = 0; mt < 4; ++mt)
#pragma unroll
        for (int nt = 0; nt < 4; ++nt) {
            int col = n0 + wn + nt * 16 + c;
            float bv = bias[col];
#pragma unroll
            for (int j = 0; j < 4; ++j) {
                int row = m0 + wm + mt * 16 + g * 4 + j;
                out_bf[(size_t)row * Kd + col] = f2bf((acc[mt][nt][j] + bv) * scale);
            }
        }
}

// ---------------------------------------------------------------------------
// Fused K+V projection, bf16 A + direct V^T (key-permuted) epilogue.
// 64x64 tile, dual B, 24KB LDS. grid (64, 12): blockIdx.y = head.
// ---------------------------------------------------------------------------
__global__ __launch_bounds__(256, 3) void gemm_kv_kernel(
    const ushort* __restrict__ A,
    const ushort* __restrict__ Wk_, const float* __restrict__ bk_,
    const ushort* __restrict__ Wv_, const float* __restrict__ bv_,
    ushort* __restrict__ outk, ushort* __restrict__ vt)
{
    constexpr int Kd = D_MODEL;
    __shared__ __align__(16) ushort As[64 * 64];    // 8KB
    __shared__ __align__(16) ushort Bk[64 * 64];    // 8KB
    __shared__ __align__(16) ushort Bv[64 * 64];    // 8KB
    const int tid = threadIdx.x, wid = tid >> 6, l = tid & 63;
    const int g = l >> 4, c = l & 15;
    const int m0 = blockIdx.x * 64, h = blockIdx.y, n0 = h * 64;
    const int wm = (wid >> 1) * 32, wn = (wid & 1) * 32;

    f32x4 acck[2][2] = {}, accv[2][2] = {};

    for (int k0 = 0; k0 < Kd; k0 += 64) {
        __syncthreads();
#pragma unroll
        for (int it = 0; it < 2; ++it) {       // A tile bf16: 64 x 64 = 8KB
            int L = wid * 2048 + it * 1024 + l * 16;
            int row = L >> 7;
            int gb = ((L >> 4) & 7) ^ (row & 7);
            async_copy16((char*)As + wid * 2048 + it * 1024,
                         A + (size_t)(m0 + row) * Kd + k0 + gb * 8);
        }
#pragma unroll
        for (int it = 0; it < 2; ++it) {       // Bk, Bv
            int L = wid * 2048 + it * 1024 + l * 16;
            int row = L >> 7;
            int gb = ((L >> 4) & 7) ^ (row & 7);
            async_copy16((char*)Bk + wid * 2048 + it * 1024,
                         Wk_ + (size_t)(n0 + row) * Kd + k0 + gb * 8);
            async_copy16((char*)Bv + wid * 2048 + it * 1024,
                         Wv_ + (size_t)(n0 + row) * Kd + k0 + gb * 8);
        }
        __syncthreads();

        bf16x8 af[2][2], bkf[2][2], bvf[2][2];
#pragma unroll
        for (int mt = 0; mt < 2; ++mt)
#pragma unroll
            for (int ks = 0; ks < 2; ++ks) {
                int row = wm + mt * 16 + c;
                af[mt][ks] = *(const bf16x8*)((const char*)As + row * 128 +
                                              (((ks * 4 + g) ^ (row & 7)) << 4));
            }
#pragma unroll
        for (int nt = 0; nt < 2; ++nt)
#pragma unroll
            for (int ks = 0; ks < 2; ++ks) {
                int row = wn + nt * 16 + c;
                int off = row * 128 + (((ks * 4 + g) ^ (row & 7)) << 4);
                bkf[nt][ks] = *(const bf16x8*)((const char*)Bk + off);
                bvf[nt][ks] = *(const bf16x8*)((const char*)Bv + off);
            }
        __builtin_amdgcn_s_setprio(1);
#pragma unroll
        for (int mt = 0; mt < 2; ++mt)
#pragma unroll
            for (int nt = 0; nt < 2; ++nt)
#pragma unroll
                for (int ks = 0; ks < 2; ++ks) {
                    acck[mt][nt] = __builtin_amdgcn_mfma_f32_16x16x32_bf16(
                        af[mt][ks], bkf[nt][ks], acck[mt][nt], 0, 0, 0);
                    accv[mt][nt] = __builtin_amdgcn_mfma_f32_16x16x32_bf16(
                        af[mt][ks], bvf[nt][ks], accv[mt][nt], 0, 0, 0);
                }
        __builtin_amdgcn_s_setprio(0);
    }

    // K epilogue: plain [row][col] bf16 store
#pragma unroll
    for (int mt = 0; mt < 2; ++mt)
#pragma unroll
        for (int nt = 0; nt < 2; ++nt) {
            int col = n0 + wn + nt * 16 + c;
            float bbk = bk_[col];
#pragma unroll
            for (int j = 0; j < 4; ++j) {
                int row = m0 + wm + mt * 16 + 4 * g + j;
                outk[(size_t)row * Kd + col] = f2bf(acck[mt][nt][j] + bbk);
            }
        }

    // V epilogue: direct transposed, key-permuted store into vt.
    {
        int b = m0 >> 9;
        int kc = (m0 >> 7) & 3;
#pragma unroll
        for (int mt = 0; mt < 2; ++mt) {
            int kb0 = (m0 & 64) + wm + mt * 16 + 4 * g;     // chunk-local key, j=0
            int kp0 = ((kb0 >> 5) << 5) | (((kb0 >> 2) & 3) << 3) | (((kb0 >> 4) & 1) << 2);
#pragma unroll
            for (int nt = 0; nt < 2; ++nt) {
                int d = wn + nt * 16 + c;
                float bbv = bv_[n0 + d];
                unsigned u0 = cvt_pk_bf16(accv[mt][nt][0] + bbv, accv[mt][nt][1] + bbv);
                unsigned u1 = cvt_pk_bf16(accv[mt][nt][2] + bbv, accv[mt][nt][3] + bbv);
                size_t base = ((size_t)(b * NHEAD + h) * HD + d) * SEQ_K + kc * 128 + kp0;
                uint2 st2; st2.x = u0; st2.y = u1;
                *(uint2*)(vt + base) = st2;
            }
        }
    }
}

// ---------------------------------------------------------------------------
// O projection (A bf16 from attn ctx): 128x128 tile, f32 output.
// ---------------------------------------------------------------------------
__global__ __launch_bounds__(256, 2) void gemm_o_kernel(
    const ushort* __restrict__ A, const ushort* __restrict__ W,
    const float* __restrict__ bias, float* __restrict__ out_f32)
{
    constexpr int Kd = D_MODEL;
    __shared__ __align__(16) ushort As[128 * 64];
    __shared__ __align__(16) ushort Bs[128 * 64];
    const int tid = threadIdx.x, wid = tid >> 6, l = tid & 63;
    const int g = l >> 4, c = l & 15;
    const int m0 = blockIdx.x * 128, n0 = blockIdx.y * 128;
    const int wm = (wid >> 1) * 64, wn = (wid & 1) * 64;

    f32x4 acc[4][4] = {};

    for (int k0 = 0; k0 < Kd; k0 += 64) {
        __syncthreads();
#pragma unroll
        for (int it = 0; it < 4; ++it) {
            int L = wid * 4096 + it * 1024 + l * 16;
            int row = L >> 7;
            int gb = ((L >> 4) & 7) ^ (row & 7);
            async_copy16((char*)As + wid * 4096 + it * 1024,
                         A + (size_t)(m0 + row) * Kd + k0 + gb * 8);
        }
#pragma unroll
        for (int it = 0; it < 4; ++it) {
            int L = wid * 4096 + it * 1024 + l * 16;
            int row = L >> 7;
            int gb = ((L >> 4) & 7) ^ (row & 7);
            async_copy16((char*)Bs + wid * 4096 + it * 1024,
                         W + (size_t)(n0 + row) * Kd + k0 + gb * 8);
        }
        __syncthreads();

        bf16x8 af[4][2], bf[4][2];
#pragma unroll
        for (int mt = 0; mt < 4; ++mt)
#pragma unroll
            for (int ks = 0; ks < 2; ++ks) {
                int row = wm + mt * 16 + c;
                af[mt][ks] = *(const bf16x8*)((const char*)As + row * 128 +
                                              (((ks * 4 + g) ^ (row & 7)) << 4));
            }
#pragma unroll
        for (int nt = 0; nt < 4; ++nt)
#pragma unroll
            for (int ks = 0; ks < 2; ++ks) {
                int row = wn + nt * 16 + c;
                bf[nt][ks] = *(const bf16x8*)((const char*)Bs + row * 128 +
                                              (((ks * 4 + g) ^ (row & 7)) << 4));
            }
        __builtin_amdgcn_s_setprio(1);
#pragma unroll
        for (int mt = 0; mt < 4; ++mt)
#pragma unroll
            for (int nt = 0; nt < 4; ++nt) {
                acc[mt][nt] = __builtin_amdgcn_mfma_f32_16x16x32_bf16(
                    af[mt][0], bf[nt][0], acc[mt][nt], 0, 0, 0);
                acc[mt][nt] = __builtin_amdgcn_mfma_f32_16x16x32_bf16(
                    af[mt][1], bf[nt][1], acc[mt][nt], 0, 0, 0);
            }
        __builtin_amdgcn_s_setprio(0);
    }

#pragma unroll
    for (int mt = 0; mt < 4; ++mt)
#pragma unroll
        for (int nt = 0; nt < 4; ++nt) {
            int col = n0 + wn + nt * 16 + c;
            float bv = bias[col];
#pragma unroll
            for (int j = 0; j < 4; ++j) {
                int row = m0 + wm + mt * 16 + g * 4 + j;
                out_f32[(size_t)row * Kd + col] = acc[mt][nt][j] + bv;
            }
        }
}

// ---------------------------------------------------------------------------
// MFMA attention v8 (r12 proven): KVBLK=64 double-buffered (2 x 16KB = 32KB
// LDS) -> dbuf overlap AND 4 blocks/CU. 2 Q-subtiles/wave, per-kb fused
// score lifecycle, 1 barrier/chunk. Grid 1536 = 8 XCD x 192 (bijective).
// ---------------------------------------------------------------------------
__global__ __launch_bounds__(256, 4) void attn_mfma_kernel(
    const ushort* __restrict__ qb, const ushort* __restrict__ kbp,
    const ushort* __restrict__ vt, const float* __restrict__ bsim,
    ushort* __restrict__ ctx)
{
    int bid = blockIdx.x;
    int w = (bid & 7) * 192 + (bid >> 3);     // XCD swizzle: 1536 = 8 x 192
    int tile = w & 15; int rest = w >> 4; int h = rest % 12; int b = rest / 12;
    int t0 = tile * 128;
    int tid = threadIdx.x, wid = tid >> 6, l = tid & 63;
    int g = l >> 4, c = l & 15;

    // KV[i]: K chunk 8KB at [0,8192), V chunk 8KB at [8192,16384)
    __shared__ __align__(16) char KV[2][16384];

    const ushort* srck[2]; const ushort* srcv[2];
    int offk[2], offv[2];
#pragma unroll
    for (int it = 0; it < 2; ++it) {
        int L = wid * 2048 + it * 1024 + l * 16;
        int row = L >> 7;                     // 0..63 (key within 64-chunk)
        int gb = ((L >> 4) & 7) ^ (row & 7);
        srck[it] = kbp + (size_t)(b * SEQ_K + row) * D_MODEL + h * HD + gb * 8;
        offk[it] = wid * 2048 + it * 1024;
        int d = row;                          // 0..63 (d row of V^T)
        int blk = (L >> 4) & 7;
        int gblk = blk ^ (d & 7);
        srcv[it] = vt + ((size_t)((b * NHEAD + h) * HD + d)) * SEQ_K + gblk * 8;
        offv[it] = 8192 + wid * 2048 + it * 1024;
    }

    // prologue: Q (128 rows x 64 = 16KB) staged through KV[0]
#pragma unroll
    for (int it = 0; it < 4; ++it) {
        int L = wid * 4096 + it * 1024 + l * 16;
        int row = L >> 7;                     // 0..127
        int gb = ((L >> 4) & 7) ^ (row & 7);
        async_copy16(&KV[0][0] + wid * 4096 + it * 1024,
                     qb + (size_t)(b * SEQ_T + t0 + row) * D_MODEL + h * HD + gb * 8);
    }
    const float* bsrow = bsim + (size_t)(b * NHEAD + h) * SEQ_K;
    __syncthreads();                          // Q landed

    bf16x8 aq[2][2];
#pragma unroll
    for (int sub = 0; sub < 2; ++sub)
#pragma unroll
        for (int ks = 0; ks < 2; ++ks) {
            int row = wid * 32 + sub * 16 + c;
            aq[sub][ks] = *(const bf16x8*)(&KV[0][0] + row * 128 +
                                           (((ks * 4 + g) ^ (row & 7)) << 4));
        }
    __syncthreads();                          // all waves done reading Q

    // issue chunk 0 into KV[0]
#pragma unroll
    for (int it = 0; it < 2; ++it) {
        async_copy16(&KV[0][0] + offk[it], srck[it]);
        async_copy16(&KV[0][0] + offv[it], srcv[it]);
    }

    const bf16x8 ones8 = {(short)0x3F80, (short)0x3F80, (short)0x3F80, (short)0x3F80,
                          (short)0x3F80, (short)0x3F80, (short)0x3F80, (short)0x3F80};
    f32x4 oacc[2][4] = {};
    f32x4 oSum[2] = {};
    int cur = 0;

    for (int kc = 0; kc < 8; ++kc) {
        __syncthreads();   // chunk kc landed (vmcnt drained); KV[cur^1] free
        if (kc < 7) {
            int nxt = cur ^ 1;
#pragma unroll
            for (int it = 0; it < 2; ++it) {
                srck[it] += 64 * D_MODEL;
                async_copy16(&KV[nxt][0] + offk[it], srck[it]);
                srcv[it] += 64;
                async_copy16(&KV[nxt][0] + offv[it], srcv[it]);
            }
        }
        const char* Kb = &KV[cur][0];
        const char* Vb = &KV[cur][0] + 8192;

#pragma unroll
        for (int kb = 0; kb < 2; ++kb) {
            // QK^T (swapped) nt = 2kb, 2kb+1; bias via MFMA C-init
            f32x4 st[2][2];
            __builtin_amdgcn_s_setprio(1);
#pragma unroll
            for (int n2 = 0; n2 < 2; ++n2) {
                int nt = 2 * kb + n2;
                f32x4 cinit = *(const f32x4*)(bsrow + kc * 64 + nt * 16 + 4 * g);
                int krow = nt * 16 + c;
                bf16x8 ak0 = *(const bf16x8*)(Kb + krow * 128 +
                                              ((g ^ (krow & 7)) << 4));
                bf16x8 ak1 = *(const bf16x8*)(Kb + krow * 128 +
                                              (((4 + g) ^ (krow & 7)) << 4));
#pragma unroll
                for (int sub = 0; sub < 2; ++sub) {
                    st[sub][n2] = __builtin_amdgcn_mfma_f32_16x16x32_bf16(
                        ak0, aq[sub][0], cinit, 0, 0, 0);
                    st[sub][n2] = __builtin_amdgcn_mfma_f32_16x16x32_bf16(
                        ak1, aq[sub][1], st[sub][n2], 0, 0, 0);
                }
            }
            __builtin_amdgcn_s_setprio(0);

            // exp2 (no max shift: bounded scores, shift-invariant) + pack
            bf16x8 pa[2];
#pragma unroll
            for (int sub = 0; sub < 2; ++sub) {
                f32x4 e0, e1;
#pragma unroll
                for (int j = 0; j < 4; ++j) {
                    e0[j] = exp2_fast(st[sub][0][j]);
                    e1[j] = exp2_fast(st[sub][1][j]);
                }
                union { unsigned u[4]; bf16x8 v; } pk;
                pk.u[0] = cvt_pk_bf16(e0[0], e0[1]);
                pk.u[1] = cvt_pk_bf16(e0[2], e0[3]);
                pk.u[2] = cvt_pk_bf16(e1[0], e1[1]);
                pk.u[3] = cvt_pk_bf16(e1[2], e1[3]);
                pa[sub] = pk.v;
            }

            // PV(kb) + row-sum; V fragment shared across both subtiles
            __builtin_amdgcn_s_setprio(1);
#pragma unroll
            for (int sub = 0; sub < 2; ++sub)
                oSum[sub] = __builtin_amdgcn_mfma_f32_16x16x32_bf16(
                    pa[sub], ones8, oSum[sub], 0, 0, 0);
#pragma unroll
            for (int dt = 0; dt < 4; ++dt) {
                int d = dt * 16 + c;
                int blk = kb * 4 + g;                 // 0..7
                int sb = blk ^ (d & 7);
                bf16x8 bv = *(const bf16x8*)(Vb + d * 128 + (sb << 4));
#pragma unroll
                for (int sub = 0; sub < 2; ++sub)
                    oacc[sub][dt] = __builtin_amdgcn_mfma_f32_16x16x32_bf16(
                        pa[sub], bv, oacc[sub][dt], 0, 0, 0);
            }
            __builtin_amdgcn_s_setprio(0);
        }
        cur ^= 1;
    }

#pragma unroll
    for (int sub = 0; sub < 2; ++sub) {
        f32x4 invL;
#pragma unroll
        for (int j = 0; j < 4; ++j) invL[j] = 1.f / oSum[sub][j];
#pragma unroll
        for (int dt = 0; dt < 4; ++dt)
#pragma unroll
            for (int j = 0; j < 4; ++j) {
                int trow = t0 + wid * 32 + sub * 16 + 4 * g + j;
                int d = dt * 16 + c;
                ctx[(size_t)(b * SEQ_T + trow) * D_MODEL + h * HD + d] =
                    f2bf(oacc[sub][dt][j] * invL[j]);
            }
    }
}

// ---------------------------------------------------------------------------
extern "C" void kernel_launch(void* const* d_in, const int* in_sizes, int n_in,
                              void* d_out, int out_size, void* d_ws, size_t ws_size,
                              hipStream_t stream)
{
    const float* hidden  = (const float*)d_in[0];
    const float* pooled  = (const float*)d_in[2];
    const float* kg_key  = (const float*)d_in[3];
    const float* kg_val  = (const float*)d_in[4];
    const float* beta    = (const float*)d_in[5];
    const float* Wq = (const float*)d_in[6];  const float* bq = (const float*)d_in[7];
    const float* Wk = (const float*)d_in[8];  const float* bk = (const float*)d_in[9];
    const float* Wv = (const float*)d_in[10]; const float* bv = (const float*)d_in[11];
    const float* Wo = (const float*)d_in[12]; const float* bo = (const float*)d_in[13];
    float* out = (float*)d_out;

    const size_t MQ = (size_t)BS * SEQ_T;   // 16384
    const size_t MK = (size_t)BS * SEQ_K;   // 4096
    const size_t DW = D_MODEL * D_MODEL;

    float*  bsim = (float*)d_ws;                     // [8][12][512] f32
    ushort* wqb  = (ushort*)(bsim + BS * NHEAD * SEQ_K);
    ushort* wkb  = wqb + DW;
    ushort* wvb  = wkb + DW;
    ushort* wob  = wvb + DW;
    ushort* hb   = wob + DW;                         // hidden bf16
    ushort* gb   = hb  + MQ * D_MODEL;               // kg_val bf16
    ushort* qbb  = gb  + MK * D_MODEL;
    ushort* kbb  = qbb + MQ * D_MODEL;
    ushort* vtb  = kbb + MK * D_MODEL;
    ushort* ctxb = vtb + MK * D_MODEL;

    // 1. conversions: weights (4) + activations (hidden, kg_val)
    cvt4_kernel<<<dim3(DW / 4 / 256, 4), 256, 0, stream>>>(
        Wq, Wk, Wv, Wo, wqb, wkb, wvb, wob);
    cvt2_kernel<<<dim3(2048, 2), 256, 0, stream>>>(
        hidden, hb, (int)(MQ * D_MODEL / 4), kg_val, gb, (int)(MK * D_MODEL / 4));

    // 2. cosine-similarity bias table (premultiplied by beta[h]*log2e)
    sim_kernel<<<(BS * SEQ_K) / 4, 256, 0, stream>>>(pooled, kg_key, beta, bsim);

    // 3. projections (pure bf16 GEMMs — r13 lesson: f32 A-staging re-paid
    //    conversion 6x per element across column blocks)
    gemm_q_kernel<<<dim3(MQ / 128, 6), 256, 0, stream>>>(
        hb, wqb, bq, qbb, 0.125f * LOG2E);
    gemm_kv_kernel<<<dim3(MK / 64, 12), 256, 0, stream>>>(
        gb, wkb, bk, wvb, bv, kbb, vtb);

    // 4. attention (KVBLK=64 dbuf, 2 subtiles/wave, 4 blocks/CU)
    attn_mfma_kernel<<<BS * NHEAD * (SEQ_T / 128), 256, 0, stream>>>(
        qbb, kbb, vtb, bsim, ctxb);

    // 5. output projection (f32 out)
    gemm_o_kernel<<<dim3(MQ / 128, 6), 256, 0, stream>>>(ctxb, wob, bo, out);
}

// Round 15
// 118.147 us; speedup vs baseline: 1.0688x; 1.0688x over previous
//
#include <hip/hip_runtime.h>
#include <math.h>

#define D_MODEL 768
#define NHEAD   12
#define HD      64
#define SEQ_T   2048
#define SEQ_K   512
#define BS      8
#define EPS_COS 1e-8f
#define LOG2E   1.44269504f

typedef short  bf16x8 __attribute__((ext_vector_type(8)));
typedef float  f32x4  __attribute__((ext_vector_type(4)));

__device__ __forceinline__ ushort f2bf(float x) {
    unsigned b = __float_as_uint(x);
    return (ushort)((b + 0x7FFF + ((b >> 16) & 1)) >> 16);
}
__device__ __forceinline__ unsigned cvt_pk_bf16(float lo, float hi) {
    unsigned r;
    asm("v_cvt_pk_bf16_f32 %0, %1, %2" : "=v"(r) : "v"(lo), "v"(hi));
    return r;
}
__device__ __forceinline__ float exp2_fast(float x) {
    float r;
    asm("v_exp_f32 %0, %1" : "=v"(r) : "v"(x));
    return r;
}

// async global->LDS 16B/lane: dest = wave-uniform base + lane*16, src per-lane
__device__ __forceinline__ void async_copy16(void* lds_base, const void* g_src) {
    __builtin_amdgcn_global_load_lds(
        (const __attribute__((address_space(1))) unsigned int*)g_src,
        (__attribute__((address_space(3))) unsigned int*)lds_base,
        16, 0, 0);
}

// ---------------------------------------------------------------------------
// 4 weight tensors f32->bf16 in one launch: grid (576, 4)
// ---------------------------------------------------------------------------
__global__ __launch_bounds__(256) void cvt4_kernel(
    const float* __restrict__ s0, const float* __restrict__ s1,
    const float* __restrict__ s2, const float* __restrict__ s3,
    ushort* __restrict__ d0, ushort* __restrict__ d1,
    ushort* __restrict__ d2, ushort* __restrict__ d3)
{
    const float* s; ushort* d;
    switch (blockIdx.y) {
        case 0: s = s0; d = d0; break;
        case 1: s = s1; d = d1; break;
        case 2: s = s2; d = d2; break;
        default: s = s3; d = d3; break;
    }
    int i = blockIdx.x * 256 + threadIdx.x;
    float4 v = reinterpret_cast<const float4*>(s)[i];
    ushort4 o;
    o.x = f2bf(v.x); o.y = f2bf(v.y); o.z = f2bf(v.z); o.w = f2bf(v.w);
    reinterpret_cast<ushort4*>(d)[i] = o;
}

// ---------------------------------------------------------------------------
// Fused kernel (r12 structure, KV branch upgraded to 128x128 concat-N):
//   blocks 0..767    : Q projection, 128x128 tile, A=hidden (f32-staged)
//   blocks 768..1151 : K|V projection, 128x128 tile over concat N=1536,
//                      A=kg_val (f32-staged); W = Wk (n<768) else Wv.
//   blocks 1152..2175: cosine-sim bias table
// 48KB LDS union; per-block uniform branch. r13/r14 lesson: separate
// launches expose the KV kernel's low efficiency; co-dispatch hides it.
// ---------------------------------------------------------------------------
__global__ __launch_bounds__(256, 3) void fused_proj_sim_kernel(
    const float* __restrict__ hidden, const float* __restrict__ kg_val,
    const ushort* __restrict__ Wqb, const float* __restrict__ bq,
    const ushort* __restrict__ Wkb, const float* __restrict__ bk_,
    const ushort* __restrict__ Wvb, const float* __restrict__ bv_,
    const float* __restrict__ pooled, const float* __restrict__ kg_key,
    const float* __restrict__ beta,
    ushort* __restrict__ qout, ushort* __restrict__ kout,
    ushort* __restrict__ vtout, float* __restrict__ bsim, float qscale)
{
    __shared__ __align__(16) char lds[49152];
    constexpr int Kd = D_MODEL;
    const int bid = blockIdx.x;
    const int tid = threadIdx.x, wid = tid >> 6, l = tid & 63;
    const int g = l >> 4, c = l & 15;

    if (bid < 1152) {
        // ---------------- GEMM path (Q or K|V): 128x128, f32-A -------------
        float*  AsF = (float*)lds;                  // 32KB
        ushort* Bs  = (ushort*)(lds + 32768);       // 16KB
        const bool isQ = bid < 768;
        int m0, n0c;
        const float* Asrc;
        const ushort* Wsel;
        if (isQ) {
            m0 = (bid & 127) * 128; n0c = (bid >> 7) * 128;
            Asrc = hidden;
            Wsel = Wqb + (size_t)n0c * Kd;
        } else {
            int q = bid - 768;
            m0 = (q & 31) * 128; n0c = (q >> 5) * 128;   // concat col 0..1535
            Asrc = kg_val;
            Wsel = (n0c < 768) ? (Wkb + (size_t)n0c * Kd)
                               : (Wvb + (size_t)(n0c - 768) * Kd);
        }
        const int wm = (wid >> 1) * 64, wn = (wid & 1) * 64;

        f32x4 acc[4][4] = {};
        for (int k0 = 0; k0 < Kd; k0 += 64) {
            __syncthreads();
#pragma unroll
            for (int it = 0; it < 8; ++it) {       // A tile f32: 128 x 64
                int L = wid * 8192 + it * 1024 + l * 16;
                int row = L >> 8;
                int blk = (L >> 4) & 15;
                int gb = (blk & 8) | ((blk & 7) ^ (row & 7));
                async_copy16((char*)AsF + wid * 8192 + it * 1024,
                             Asrc + (size_t)(m0 + row) * Kd + k0 + gb * 4);
            }
#pragma unroll
            for (int it = 0; it < 4; ++it) {       // B tile bf16: 128 x 64
                int L = wid * 4096 + it * 1024 + l * 16;
                int row = L >> 7;
                int gb = ((L >> 4) & 7) ^ (row & 7);
                async_copy16((char*)Bs + wid * 4096 + it * 1024,
                             Wsel + (size_t)row * Kd + k0 + gb * 8);
            }
            __syncthreads();

            bf16x8 af[4][2], bf[4][2];
#pragma unroll
            for (int mt = 0; mt < 4; ++mt)
#pragma unroll
                for (int ks = 0; ks < 2; ++ks) {
                    int row = wm + mt * 16 + c;
                    int b0 = ks * 8 + 2 * g;
                    int p0 = (b0 & 8) | ((b0 & 7) ^ (row & 7));
                    int p1 = (b0 & 8) | (((b0 + 1) & 7) ^ (row & 7));
                    f32x4 a0 = *(const f32x4*)((const char*)AsF + row * 256 + (p0 << 4));
                    f32x4 a1 = *(const f32x4*)((const char*)AsF + row * 256 + (p1 << 4));
                    union { unsigned u[4]; bf16x8 v; } t;
                    t.u[0] = cvt_pk_bf16(a0[0], a0[1]);
                    t.u[1] = cvt_pk_bf16(a0[2], a0[3]);
                    t.u[2] = cvt_pk_bf16(a1[0], a1[1]);
                    t.u[3] = cvt_pk_bf16(a1[2], a1[3]);
                    af[mt][ks] = t.v;
                }
#pragma unroll
            for (int nt = 0; nt < 4; ++nt)
#pragma unroll
                for (int ks = 0; ks < 2; ++ks) {
                    int row = wn + nt * 16 + c;
                    bf[nt][ks] = *(const bf16x8*)((const char*)Bs + row * 128 +
                                                  (((ks * 4 + g) ^ (row & 7)) << 4));
                }
            __builtin_amdgcn_s_setprio(1);
#pragma unroll
            for (int mt = 0; mt < 4; ++mt)
#pragma unroll
                for (int nt = 0; nt < 4; ++nt) {
                    acc[mt][nt] = __builtin_amdgcn_mfma_f32_16x16x32_bf16(
                        af[mt][0], bf[nt][0], acc[mt][nt], 0, 0, 0);
                    acc[mt][nt] = __builtin_amdgcn_mfma_f32_16x16x32_bf16(
                        af[mt][1], bf[nt][1], acc[mt][nt], 0, 0, 0);
                }
            __builtin_amdgcn_s_setprio(0);
        }

        if (isQ) {
#pragma unroll
            for (int mt = 0; mt < 4; ++mt)
#pragma unroll
                for (int nt = 0; nt < 4; ++nt) {
                    int col = n0c + wn + nt * 16 + c;
                    float bv = bq[col];
#pragma unroll
                    for (int j = 0; j < 4; ++j) {
                        int row = m0 + wm + mt * 16 + g * 4 + j;
                        qout[(size_t)row * Kd + col] =
                            f2bf((acc[mt][nt][j] + bv) * qscale);
                    }
                }
        } else if (n0c < 768) {
            // K epilogue: plain [row][col] bf16 store
#pragma unroll
            for (int mt = 0; mt < 4; ++mt)
#pragma unroll
                for (int nt = 0; nt < 4; ++nt) {
                    int col = n0c + wn + nt * 16 + c;
                    float bbk = bk_[col];
#pragma unroll
                    for (int j = 0; j < 4; ++j) {
                        int row = m0 + wm + mt * 16 + g * 4 + j;
                        kout[(size_t)row * Kd + col] = f2bf(acc[mt][nt][j] + bbk);
                    }
                }
        } else {
            // V epilogue: transposed, key-permuted store into vt.
            // key = 32u+16s+4v+t -> key' = 32u+8v+4s+t; j maps to 4
            // consecutive key' positions -> one 8B store per (mt,nt).
            int b = m0 >> 9;
            int kc = (m0 >> 7) & 3;
#pragma unroll
            for (int mt = 0; mt < 4; ++mt) {
                int kb0 = wm + mt * 16 + 4 * g;          // chunk-local key, j=0
                int kp0 = ((kb0 >> 5) << 5) | (((kb0 >> 2) & 3) << 3) |
                          (((kb0 >> 4) & 1) << 2);
#pragma unroll
                for (int nt = 0; nt < 4; ++nt) {
                    int d_full = (n0c - 768) + wn + nt * 16 + c;   // 0..767
                    int h2 = d_full >> 6, dd = d_full & 63;
                    float bbv = bv_[d_full];
                    unsigned u0 = cvt_pk_bf16(acc[mt][nt][0] + bbv,
                                              acc[mt][nt][1] + bbv);
                    unsigned u1 = cvt_pk_bf16(acc[mt][nt][2] + bbv,
                                              acc[mt][nt][3] + bbv);
                    size_t base = ((size_t)(b * NHEAD + h2) * HD + dd) * SEQ_K
                                  + kc * 128 + kp0;
                    uint2 st2; st2.x = u0; st2.y = u1;
                    *(uint2*)(vtout + base) = st2;
                }
            }
        }
    } else {
        // ---------------- cosine similarity -> bsim table -------------------
        int wrow = (bid - 1152) * 4 + (tid >> 6);   // 0..4095
        int lane = tid & 63;
        int b  = wrow >> 9;
        int kk = wrow & 511;
        const float* p   = pooled + (size_t)b * D_MODEL;
        const float* key = kg_key + ((size_t)b * SEQ_K + kk) * D_MODEL;
        float dpk = 0.f, dkk = 0.f, dpp = 0.f;
        for (int i = lane; i < D_MODEL; i += 64) {
            float pv = p[i], kv = key[i];
            dpk += pv * kv; dkk += kv * kv; dpp += pv * pv;
        }
        for (int off = 32; off; off >>= 1) {
            dpk += __shfl_xor(dpk, off);
            dkk += __shfl_xor(dkk, off);
            dpp += __shfl_xor(dpp, off);
        }
        if (lane == 0) {
            float np_ = fmaxf(sqrtf(dpp), EPS_COS);
            float nk_ = fmaxf(sqrtf(dkk), EPS_COS);
            float sv = (dpk / (np_ * nk_)) * LOG2E;
#pragma unroll
            for (int h = 0; h < NHEAD; ++h)
                bsim[(size_t)(b * NHEAD + h) * SEQ_K + kk] = beta[h] * sv;
        }
    }
}

// ---------------------------------------------------------------------------
// O projection (A bf16 from attn ctx): 128x128 tile, f32 output.
// ---------------------------------------------------------------------------
__global__ __launch_bounds__(256, 2) void gemm_o_kernel(
    const ushort* __restrict__ A, const ushort* __restrict__ W,
    const float* __restrict__ bias, float* __restrict__ out_f32)
{
    constexpr int Kd = D_MODEL;
    __shared__ __align__(16) ushort As[128 * 64];
    __shared__ __align__(16) ushort Bs[128 * 64];
    const int tid = threadIdx.x, wid = tid >> 6, l = tid & 63;
    const int g = l >> 4, c = l & 15;
    const int m0 = blockIdx.x * 128, n0 = blockIdx.y * 128;
    const int wm = (wid >> 1) * 64, wn = (wid & 1) * 64;

    f32x4 acc[4][4] = {};

    for (int k0 = 0; k0 < Kd; k0 += 64) {
        __syncthreads();
#pragma unroll
        for (int it = 0; it < 4; ++it) {
            int L = wid * 4096 + it * 1024 + l * 16;
            int row = L >> 7;
            int gb = ((L >> 4) & 7) ^ (row & 7);
            async_copy16((char*)As + wid * 4096 + it * 1024,
                         A + (size_t)(m0 + row) * Kd + k0 + gb * 8);
        }
#pragma unroll
        for (int it = 0; it < 4; ++it) {
            int L = wid * 4096 + it * 1024 + l * 16;
            int row = L >> 7;
            int gb = ((L >> 4) & 7) ^ (row & 7);
            async_copy16((char*)Bs + wid * 4096 + it * 1024,
                         W + (size_t)(n0 + row) * Kd + k0 + gb * 8);
        }
        __syncthreads();

        bf16x8 af[4][2], bf[4][2];
#pragma unroll
        for (int mt = 0; mt < 4; ++mt)
#pragma unroll
            for (int ks = 0; ks < 2; ++ks) {
                int row = wm + mt * 16 + c;
                af[mt][ks] = *(const bf16x8*)((const char*)As + row * 128 +
                                              (((ks * 4 + g) ^ (row & 7)) << 4));
            }
#pragma unroll
        for (int nt = 0; nt < 4; ++nt)
#pragma unroll
            for (int ks = 0; ks < 2; ++ks) {
                int row = wn + nt * 16 + c;
                bf[nt][ks] = *(const bf16x8*)((const char*)Bs + row * 128 +
                                              (((ks * 4 + g) ^ (row & 7)) << 4));
            }
        __builtin_amdgcn_s_setprio(1);
#pragma unroll
        for (int mt = 0; mt < 4; ++mt)
#pragma unroll
            for (int nt = 0; nt < 4; ++nt) {
                acc[mt][nt] = __builtin_amdgcn_mfma_f32_16x16x32_bf16(
                    af[mt][0], bf[nt][0], acc[mt][nt], 0, 0, 0);
                acc[mt][nt] = __builtin_amdgcn_mfma_f32_16x16x32_bf16(
                    af[mt][1], bf[nt][1], acc[mt][nt], 0, 0, 0);
            }
        __builtin_amdgcn_s_setprio(0);
    }

#pragma unroll
    for (int mt = 0; mt < 4; ++mt)
#pragma unroll
        for (int nt = 0; nt < 4; ++nt) {
            int col = n0 + wn + nt * 16 + c;
            float bv = bias[col];
#pragma unroll
            for (int j = 0; j < 4; ++j) {
                int row = m0 + wm + mt * 16 + g * 4 + j;
                out_f32[(size_t)row * Kd + col] = acc[mt][nt][j] + bv;
            }
        }
}

// ---------------------------------------------------------------------------
// MFMA attention v8 (r12 proven): KVBLK=64 double-buffered (2 x 16KB = 32KB
// LDS) -> dbuf overlap AND 4 blocks/CU. 2 Q-subtiles/wave, per-kb fused
// score lifecycle, 1 barrier/chunk. Grid 1536 = 8 XCD x 192 (bijective).
// ---------------------------------------------------------------------------
__global__ __launch_bounds__(256, 4) void attn_mfma_kernel(
    const ushort* __restrict__ qb, const ushort* __restrict__ kbp,
    const ushort* __restrict__ vt, const float* __restrict__ bsim,
    ushort* __restrict__ ctx)
{
    int bid = blockIdx.x;
    int w = (bid & 7) * 192 + (bid >> 3);     // XCD swizzle: 1536 = 8 x 192
    int tile = w & 15; int rest = w >> 4; int h = rest % 12; int b = rest / 12;
    int t0 = tile * 128;
    int tid = threadIdx.x, wid = tid >> 6, l = tid & 63;
    int g = l >> 4, c = l & 15;

    // KV[i]: K chunk 8KB at [0,8192), V chunk 8KB at [8192,16384)
    __shared__ __align__(16) char KV[2][16384];

    const ushort* srck[2]; const ushort* srcv[2];
    int offk[2], offv[2];
#pragma unroll
    for (int it = 0; it < 2; ++it) {
        int L = wid * 2048 + it * 1024 + l * 16;
        int row = L >> 7;                     // 0..63 (key within 64-chunk)
        int gb = ((L >> 4) & 7) ^ (row & 7);
        srck[it] = kbp + (size_t)(b * SEQ_K + row) * D_MODEL + h * HD + gb * 8;
        offk[it] = wid * 2048 + it * 1024;
        int d = row;                          // 0..63 (d row of V^T)
        int blk = (L >> 4) & 7;
        int gblk = blk ^ (d & 7);
        srcv[it] = vt + ((size_t)((b * NHEAD + h) * HD + d)) * SEQ_K + gblk * 8;
        offv[it] = 8192 + wid * 2048 + it * 1024;
    }

    // prologue: Q (128 rows x 64 = 16KB) staged through KV[0]
#pragma unroll
    for (int it = 0; it < 4; ++it) {
        int L = wid * 4096 + it * 1024 + l * 16;
        int row = L >> 7;                     // 0..127
        int gb = ((L >> 4) & 7) ^ (row & 7);
        async_copy16(&KV[0][0] + wid * 4096 + it * 1024,
                     qb + (size_t)(b * SEQ_T + t0 + row) * D_MODEL + h * HD + gb * 8);
    }
    const float* bsrow = bsim + (size_t)(b * NHEAD + h) * SEQ_K;
    __syncthreads();                          // Q landed

    bf16x8 aq[2][2];
#pragma unroll
    for (int sub = 0; sub < 2; ++sub)
#pragma unroll
        for (int ks = 0; ks < 2; ++ks) {
            int row = wid * 32 + sub * 16 + c;
            aq[sub][ks] = *(const bf16x8*)(&KV[0][0] + row * 128 +
                                           (((ks * 4 + g) ^ (row & 7)) << 4));
        }
    __syncthreads();                          // all waves done reading Q

    // issue chunk 0 into KV[0]
#pragma unroll
    for (int it = 0; it < 2; ++it) {
        async_copy16(&KV[0][0] + offk[it], srck[it]);
        async_copy16(&KV[0][0] + offv[it], srcv[it]);
    }

    const bf16x8 ones8 = {(short)0x3F80, (short)0x3F80, (short)0x3F80, (short)0x3F80,
                          (short)0x3F80, (short)0x3F80, (short)0x3F80, (short)0x3F80};
    f32x4 oacc[2][4] = {};
    f32x4 oSum[2] = {};
    int cur = 0;

    for (int kc = 0; kc < 8; ++kc) {
        __syncthreads();   // chunk kc landed (vmcnt drained); KV[cur^1] free
        if (kc < 7) {
            int nxt = cur ^ 1;
#pragma unroll
            for (int it = 0; it < 2; ++it) {
                srck[it] += 64 * D_MODEL;
                async_copy16(&KV[nxt][0] + offk[it], srck[it]);
                srcv[it] += 64;
                async_copy16(&KV[nxt][0] + offv[it], srcv[it]);
            }
        }
        const char* Kb = &KV[cur][0];
        const char* Vb = &KV[cur][0] + 8192;

#pragma unroll
        for (int kb = 0; kb < 2; ++kb) {
            // QK^T (swapped) nt = 2kb, 2kb+1; bias via MFMA C-init
            f32x4 st[2][2];
            __builtin_amdgcn_s_setprio(1);
#pragma unroll
            for (int n2 = 0; n2 < 2; ++n2) {
                int nt = 2 * kb + n2;
                f32x4 cinit = *(const f32x4*)(bsrow + kc * 64 + nt * 16 + 4 * g);
                int krow = nt * 16 + c;
                bf16x8 ak0 = *(const bf16x8*)(Kb + krow * 128 +
                                              ((g ^ (krow & 7)) << 4));
                bf16x8 ak1 = *(const bf16x8*)(Kb + krow * 128 +
                                              (((4 + g) ^ (krow & 7)) << 4));
#pragma unroll
                for (int sub = 0; sub < 2; ++sub) {
                    st[sub][n2] = __builtin_amdgcn_mfma_f32_16x16x32_bf16(
                        ak0, aq[sub][0], cinit, 0, 0, 0);
                    st[sub][n2] = __builtin_amdgcn_mfma_f32_16x16x32_bf16(
                        ak1, aq[sub][1], st[sub][n2], 0, 0, 0);
                }
            }
            __builtin_amdgcn_s_setprio(0);

            // exp2 (no max shift: bounded scores, shift-invariant) + pack
            bf16x8 pa[2];
#pragma unroll
            for (int sub = 0; sub < 2; ++sub) {
                f32x4 e0, e1;
#pragma unroll
                for (int j = 0; j < 4; ++j) {
                    e0[j] = exp2_fast(st[sub][0][j]);
                    e1[j] = exp2_fast(st[sub][1][j]);
                }
                union { unsigned u[4]; bf16x8 v; } pk;
                pk.u[0] = cvt_pk_bf16(e0[0], e0[1]);
                pk.u[1] = cvt_pk_bf16(e0[2], e0[3]);
                pk.u[2] = cvt_pk_bf16(e1[0], e1[1]);
                pk.u[3] = cvt_pk_bf16(e1[2], e1[3]);
                pa[sub] = pk.v;
            }

            // PV(kb) + row-sum; V fragment shared across both subtiles
            __builtin_amdgcn_s_setprio(1);
#pragma unroll
            for (int sub = 0; sub < 2; ++sub)
                oSum[sub] = __builtin_amdgcn_mfma_f32_16x16x32_bf16(
                    pa[sub], ones8, oSum[sub], 0, 0, 0);
#pragma unroll
            for (int dt = 0; dt < 4; ++dt) {
                int d = dt * 16 + c;
                int blk = kb * 4 + g;                 // 0..7
                int sb = blk ^ (d & 7);
                bf16x8 bv = *(const bf16x8*)(Vb + d * 128 + (sb << 4));
#pragma unroll
                for (int sub = 0; sub < 2; ++sub)
                    oacc[sub][dt] = __builtin_amdgcn_mfma_f32_16x16x32_bf16(
                        pa[sub], bv, oacc[sub][dt], 0, 0, 0);
            }
            __builtin_amdgcn_s_setprio(0);
        }
        cur ^= 1;
    }

#pragma unroll
    for (int sub = 0; sub < 2; ++sub) {
        f32x4 invL;
#pragma unroll
        for (int j = 0; j < 4; ++j) invL[j] = 1.f / oSum[sub][j];
#pragma unroll
        for (int dt = 0; dt < 4; ++dt)
#pragma unroll
            for (int j = 0; j < 4; ++j) {
                int trow = t0 + wid * 32 + sub * 16 + 4 * g + j;
                int d = dt * 16 + c;
                ctx[(size_t)(b * SEQ_T + trow) * D_MODEL + h * HD + d] =
                    f2bf(oacc[sub][dt][j] * invL[j]);
            }
    }
}

// ---------------------------------------------------------------------------
extern "C" void kernel_launch(void* const* d_in, const int* in_sizes, int n_in,
                              void* d_out, int out_size, void* d_ws, size_t ws_size,
                              hipStream_t stream)
{
    const float* hidden  = (const float*)d_in[0];
    const float* pooled  = (const float*)d_in[2];
    const float* kg_key  = (const float*)d_in[3];
    const float* kg_val  = (const float*)d_in[4];
    const float* beta    = (const float*)d_in[5];
    const float* Wq = (const float*)d_in[6];  const float* bq = (const float*)d_in[7];
    const float* Wk = (const float*)d_in[8];  const float* bk = (const float*)d_in[9];
    const float* Wv = (const float*)d_in[10]; const float* bv = (const float*)d_in[11];
    const float* Wo = (const float*)d_in[12]; const float* bo = (const float*)d_in[13];
    float* out = (float*)d_out;

    const size_t MQ = (size_t)BS * SEQ_T;   // 16384
    const size_t MK = (size_t)BS * SEQ_K;   // 4096
    const size_t DW = D_MODEL * D_MODEL;

    float*  bsim = (float*)d_ws;                     // [8][12][512] f32
    ushort* wqb  = (ushort*)(bsim + BS * NHEAD * SEQ_K);
    ushort* wkb  = wqb + DW;
    ushort* wvb  = wkb + DW;
    ushort* wob  = wvb + DW;
    ushort* qbb  = wob + DW;
    ushort* kbb  = qbb + MQ * D_MODEL;
    ushort* vtb  = kbb + MK * D_MODEL;
    ushort* ctxb = vtb + MK * D_MODEL;

    // 1. weight conversions
    cvt4_kernel<<<dim3(DW / 4 / 256, 4), 256, 0, stream>>>(
        Wq, Wk, Wv, Wo, wqb, wkb, wvb, wob);

    // 2. fused: Q-proj + KV-proj (concat-N 128x128) + sim — one launch so
    //    KV blocks co-schedule with Q blocks (r12/r13 lesson)
    fused_proj_sim_kernel<<<2176, 256, 0, stream>>>(
        hidden, kg_val, wqb, bq, wkb, bk, wvb, bv,
        pooled, kg_key, beta, qbb, kbb, vtb, bsim, 0.125f * LOG2E);

    // 3. attention (KVBLK=64 dbuf, 2 subtiles/wave, 4 blocks/CU)
    attn_mfma_kernel<<<BS * NHEAD * (SEQ_T / 128), 256, 0, stream>>>(
        qbb, kbb, vtb, bsim, ctxb);

    // 4. output projection (f32 out)
    gemm_o_kernel<<<dim3(MQ / 128, 6), 256, 0, stream>>>(ctxb, wob, bo, out);
}